// Round 2
// baseline (420.817 us; speedup 1.0000x reference)
//
#include <hip/hip_runtime.h>

// Problem constants (match reference setup_inputs)
#define NSAMP 65536
#define DDIM  128

// Half-wave (32 lanes) per TWO samples; lane l owns elements {4l..4l+3} as float4.
// All 14 row-gathers (+6 int2 index loads) for both samples are issued before any
// compute, doubling per-wave outstanding misses vs the 1-sample version.
// Projection is linear in x, so project (h + r - t) once per score.
__global__ __launch_bounds__(256) void transh_kernel(
    const int* __restrict__ pos_h, const int* __restrict__ pos_t, const int* __restrict__ pos_r,
    const int* __restrict__ neg_h, const int* __restrict__ neg_t, const int* __restrict__ neg_r,
    const float* __restrict__ ent, const float* __restrict__ vvrel, const float* __restrict__ bases,
    float* __restrict__ out)
{
    const int tid  = blockIdx.x * blockDim.x + threadIdx.x;
    const int pair = tid >> 5;            // half-wave index == sample-pair index
    const int sub  = threadIdx.x & 31;    // lane within the 32-lane group
    const int s0   = pair << 1;           // even sample
    if (s0 >= NSAMP) return;

    // Index loads: two consecutive samples per stream as one aligned int2.
    const int2 phI = *(const int2*)(pos_h + s0);
    const int2 ptI = *(const int2*)(pos_t + s0);
    const int2 prI = *(const int2*)(pos_r + s0);
    const int2 nhI = *(const int2*)(neg_h + s0);
    const int2 ntI = *(const int2*)(neg_t + s0);
    const int2 nrI = *(const int2*)(neg_r + s0);

    // ---- issue all 14 row gathers up front (compiler overlaps via vmcnt) ----
    // sample 0
    const float4 v0  = ((const float4*)(bases + (size_t)prI.x * DDIM))[sub];
    const float4 a0  = ((const float4*)(ent   + (size_t)phI.x * DDIM))[sub];
    const float4 c0  = ((const float4*)(ent   + (size_t)ptI.x * DDIM))[sub];
    const float4 b0  = ((const float4*)(vvrel + (size_t)prI.x * DDIM))[sub];
    const float4 na0 = ((const float4*)(ent   + (size_t)nhI.x * DDIM))[sub];
    const float4 nc0 = ((const float4*)(ent   + (size_t)ntI.x * DDIM))[sub];
    const float4 nb0 = ((const float4*)(vvrel + (size_t)nrI.x * DDIM))[sub];
    // sample 1
    const float4 v1  = ((const float4*)(bases + (size_t)prI.y * DDIM))[sub];
    const float4 a1  = ((const float4*)(ent   + (size_t)phI.y * DDIM))[sub];
    const float4 c1  = ((const float4*)(ent   + (size_t)ptI.y * DDIM))[sub];
    const float4 b1  = ((const float4*)(vvrel + (size_t)prI.y * DDIM))[sub];
    const float4 na1 = ((const float4*)(ent   + (size_t)nhI.y * DDIM))[sub];
    const float4 nc1 = ((const float4*)(ent   + (size_t)ntI.y * DDIM))[sub];
    const float4 nb1 = ((const float4*)(vvrel + (size_t)nrI.y * DDIM))[sub];

    // ---- sample 0 partials ----
    float4 sp0, sn0;
    sp0.x = a0.x + b0.x - c0.x;   sp0.y = a0.y + b0.y - c0.y;
    sp0.z = a0.z + b0.z - c0.z;   sp0.w = a0.w + b0.w - c0.w;
    sn0.x = na0.x + nb0.x - nc0.x; sn0.y = na0.y + nb0.y - nc0.y;
    sn0.z = na0.z + nb0.z - nc0.z; sn0.w = na0.w + nb0.w - nc0.w;

    float vv0  = v0.x * v0.x + v0.y * v0.y + v0.z * v0.z + v0.w * v0.w;
    float vsp0 = v0.x * sp0.x + v0.y * sp0.y + v0.z * sp0.z + v0.w * sp0.w;
    float vsn0 = v0.x * sn0.x + v0.y * sn0.y + v0.z * sn0.z + v0.w * sn0.w;

    // ---- sample 1 partials ----
    float4 sp1, sn1;
    sp1.x = a1.x + b1.x - c1.x;   sp1.y = a1.y + b1.y - c1.y;
    sp1.z = a1.z + b1.z - c1.z;   sp1.w = a1.w + b1.w - c1.w;
    sn1.x = na1.x + nb1.x - nc1.x; sn1.y = na1.y + nb1.y - nc1.y;
    sn1.z = na1.z + nb1.z - nc1.z; sn1.w = na1.w + nb1.w - nc1.w;

    float vv1  = v1.x * v1.x + v1.y * v1.y + v1.z * v1.z + v1.w * v1.w;
    float vsp1 = v1.x * sp1.x + v1.y * sp1.y + v1.z * sp1.z + v1.w * sp1.w;
    float vsn1 = v1.x * sn1.x + v1.y * sn1.y + v1.z * sn1.z + v1.w * sn1.w;

    // 32-lane butterfly (xor offsets <=16 stay within the half-wave)
    #pragma unroll
    for (int off = 16; off > 0; off >>= 1) {
        vv0  += __shfl_xor(vv0,  off, 64);
        vsp0 += __shfl_xor(vsp0, off, 64);
        vsn0 += __shfl_xor(vsn0, off, 64);
        vv1  += __shfl_xor(vv1,  off, 64);
        vsp1 += __shfl_xor(vsp1, off, 64);
        vsn1 += __shfl_xor(vsn1, off, 64);
    }

    const float cp0 = vsp0 / vv0;
    const float cn0 = vsn0 / vv0;
    const float cp1 = vsp1 / vv1;
    const float cn1 = vsn1 / vv1;

    float ap0 = fabsf(sp0.x - cp0 * v0.x) + fabsf(sp0.y - cp0 * v0.y)
              + fabsf(sp0.z - cp0 * v0.z) + fabsf(sp0.w - cp0 * v0.w);
    float an0 = fabsf(sn0.x - cn0 * v0.x) + fabsf(sn0.y - cn0 * v0.y)
              + fabsf(sn0.z - cn0 * v0.z) + fabsf(sn0.w - cn0 * v0.w);
    float ap1 = fabsf(sp1.x - cp1 * v1.x) + fabsf(sp1.y - cp1 * v1.y)
              + fabsf(sp1.z - cp1 * v1.z) + fabsf(sp1.w - cp1 * v1.w);
    float an1 = fabsf(sn1.x - cn1 * v1.x) + fabsf(sn1.y - cn1 * v1.y)
              + fabsf(sn1.z - cn1 * v1.z) + fabsf(sn1.w - cn1 * v1.w);

    #pragma unroll
    for (int off = 16; off > 0; off >>= 1) {
        ap0 += __shfl_xor(ap0, off, 64);
        an0 += __shfl_xor(an0, off, 64);
        ap1 += __shfl_xor(ap1, off, 64);
        an1 += __shfl_xor(an1, off, 64);
    }

    if (sub == 0) {
        // s0 is even -> 8B-aligned float2 stores (pos pair, then neg pair)
        *(float2*)(out + s0)         = make_float2(ap0, ap1);
        *(float2*)(out + NSAMP + s0) = make_float2(an0, an1);
    }
}

extern "C" void kernel_launch(void* const* d_in, const int* in_sizes, int n_in,
                              void* d_out, int out_size, void* d_ws, size_t ws_size,
                              hipStream_t stream) {
    const int*   pos_h = (const int*)d_in[0];
    const int*   pos_t = (const int*)d_in[1];
    const int*   pos_r = (const int*)d_in[2];
    const int*   neg_h = (const int*)d_in[3];
    const int*   neg_t = (const int*)d_in[4];
    const int*   neg_r = (const int*)d_in[5];
    const float* ent   = (const float*)d_in[6];
    const float* vvrel = (const float*)d_in[7];
    const float* bases = (const float*)d_in[8];
    float* out = (float*)d_out;

    // Half-wave per sample-pair: 16 samples per 256-thread block
    const int threads = 256;
    const int blocks  = (NSAMP / 2 * 32) / threads;  // 4096
    transh_kernel<<<blocks, threads, 0, stream>>>(
        pos_h, pos_t, pos_r, neg_h, neg_t, neg_r, ent, vvrel, bases, out);
}